// Round 1
// baseline (45622.968 us; speedup 1.0000x reference)
//
#include <hip/hip_runtime.h>

#define BB    64
#define UU    256
#define HH    128
#define MELM  80
#define RRR   5
#define G3    768

// ---- workspace float offsets (transposed weights, then keys) ----
#define O_WP1T   0u          // [80][256]
#define O_WP2T   20480u      // [256][128]
#define O_WAIH   53248u      // [128][768]
#define O_WAHH   151552u     // [256][768]
#define O_W2T    348160u     // [256][256]
#define O_WPROJ  413696u     // [512][256]
#define O_W1IH   544768u     // [256][768]
#define O_W1HH   741376u     // [256][768]
#define O_W2IH   937984u     // [256][768]
#define O_W2HH   1134592u    // [256][768]
#define O_WOUT   1331200u    // [256][400]
#define O_W1T    1433600u    // [256][256]
#define O_KEYS   1499136u    // [64][1000][256]

__device__ __forceinline__ float fsig(float x){ return 1.0f/(1.0f+__expf(-x)); }
__device__ __forceinline__ float ftanh(float x){ return 1.0f - 2.0f/(1.0f+__expf(2.0f*x)); }

// C[j4*4 .. j4*4+3] = act[0:K] dot Wt[k][N] columns; Wt is [K][N] transposed layout.
template<int K, int N4>
__device__ __forceinline__ float4 gemv4(const float* __restrict__ Wt,
                                        const float* __restrict__ act, int j4){
  const float4* __restrict__ w = reinterpret_cast<const float4*>(Wt) + j4;
  const float4* __restrict__ a = reinterpret_cast<const float4*>(act);
  float4 acc = {0.f,0.f,0.f,0.f};
  #pragma unroll 4
  for (int k4 = 0; k4 < K/4; ++k4){
    float4 av = a[k4];
    float4 w0 = w[(4*k4+0)*N4];
    float4 w1 = w[(4*k4+1)*N4];
    float4 w2 = w[(4*k4+2)*N4];
    float4 w3 = w[(4*k4+3)*N4];
    acc.x += av.x*w0.x + av.y*w1.x + av.z*w2.x + av.w*w3.x;
    acc.y += av.x*w0.y + av.y*w1.y + av.z*w2.y + av.w*w3.y;
    acc.z += av.x*w0.z + av.y*w1.z + av.z*w2.z + av.w*w3.z;
    acc.w += av.x*w0.w + av.y*w1.w + av.z*w2.w + av.w*w3.w;
  }
  return acc;
}

__global__ void k_transpose(const float* __restrict__ src, float* __restrict__ dst,
                            int N, int K){
  int idx = blockIdx.x*blockDim.x + threadIdx.x;
  if (idx < N*K){
    int n = idx / K, k = idx - n*K;
    dst[k*N + n] = src[idx];
  }
}

// keys[b][t][c] = sum_u mem[b][t][u] * W1[c][u]  (uses W1t = [u][c])
// block: 128 t-rows x 128 cols, 256 threads, 8x8 register tile, no LDS (L1-resident rows)
__global__ __launch_bounds__(256) void k_keys(const float* __restrict__ mem,
      const float* __restrict__ W1t, float* __restrict__ keys, int T)
{
  const int b = blockIdx.z;
  const int tbase = blockIdx.x * 128;
  const int cbase = blockIdx.y * 128;
  const int tid = threadIdx.x;
  const int rt = tid >> 4, ct = tid & 15;
  const float* memb = mem + (size_t)b*T*UU;

  float acc[8][8];
  #pragma unroll
  for (int i=0;i<8;i++){
    #pragma unroll
    for (int j=0;j<8;j++) acc[i][j]=0.f;
  }

  const float* arow[8];
  #pragma unroll
  for (int i=0;i<8;i++){
    int t = tbase + rt*8 + i;
    arow[i] = memb + (size_t)(t < T ? t : T-1)*UU;
  }
  const float* wcol = W1t + cbase + ct*8;

  for (int k=0;k<UU;k+=4){
    float w8[4][8];
    #pragma unroll
    for (int kk=0;kk<4;kk++){
      float4 lo = *reinterpret_cast<const float4*>(wcol + (size_t)(k+kk)*UU);
      float4 hi = *reinterpret_cast<const float4*>(wcol + (size_t)(k+kk)*UU + 4);
      w8[kk][0]=lo.x; w8[kk][1]=lo.y; w8[kk][2]=lo.z; w8[kk][3]=lo.w;
      w8[kk][4]=hi.x; w8[kk][5]=hi.y; w8[kk][6]=hi.z; w8[kk][7]=hi.w;
    }
    #pragma unroll
    for (int i=0;i<8;i++){
      float4 a = *reinterpret_cast<const float4*>(arow[i] + k);
      float a4[4] = {a.x, a.y, a.z, a.w};
      #pragma unroll
      for (int kk=0;kk<4;kk++){
        #pragma unroll
        for (int j=0;j<8;j++) acc[i][j] += a4[kk]*w8[kk][j];
      }
    }
  }
  #pragma unroll
  for (int i=0;i<8;i++){
    int t = tbase + rt*8 + i;
    if (t < T){
      float* dst = keys + (size_t)b*T*UU + (size_t)t*UU + cbase + ct*8;
      float4 lo = {acc[i][0],acc[i][1],acc[i][2],acc[i][3]};
      float4 hi = {acc[i][4],acc[i][5],acc[i][6],acc[i][7]};
      *reinterpret_cast<float4*>(dst)   = lo;
      *reinterpret_cast<float4*>(dst+4) = hi;
    }
  }
}

// persistent decoder: one block per batch element, 1024 threads, 200 steps in-loop
__global__ __launch_bounds__(1024) void k_decode(
    const float* __restrict__ mem, const float* __restrict__ ws,
    const float* __restrict__ bp1, const float* __restrict__ bp2,
    const float* __restrict__ vvec,
    const float* __restrict__ ba_ih, const float* __restrict__ ba_hh,
    const float* __restrict__ b1_ih, const float* __restrict__ b1_hh,
    const float* __restrict__ b2_ih, const float* __restrict__ b2_hh,
    const float* __restrict__ bproj, const float* __restrict__ bout,
    float* __restrict__ out, int T, int steps)
{
  __shared__ __align__(16) float s_prev[MELM];
  __shared__ __align__(16) float s_x1[UU];
  __shared__ __align__(16) float s_x[HH];
  __shared__ __align__(16) float s_ha[UU];     // attn hidden == d_t after update
  __shared__ __align__(16) float s_q[UU];
  __shared__ __align__(16) float s_gi[G3];
  __shared__ __align__(16) float s_gha[G3];
  __shared__ __align__(16) float s_gh1[G3];
  __shared__ __align__(16) float s_gh2[G3];
  __shared__ __align__(16) float s_g1h[UU];
  __shared__ __align__(16) float s_g2h[UU];
  __shared__ __align__(16) float s_g1in[UU];
  __shared__ __align__(16) float s_g2in[UU];
  __shared__ __align__(16) float s_s2[UU];
  __shared__ __align__(16) float s_ctx[UU];
  __shared__ __align__(16) float s_sc[1024];
  __shared__ __align__(16) float s_red[16*UU];
  __shared__ float s_wred[16];
  __shared__ float s_scal[2];   // [0]=max, [1]=1/sum

  const int b = blockIdx.x;
  const int tid = threadIdx.x;
  const int lane = tid & 63;
  const int wid = tid >> 6;

  const float* __restrict__ keys = ws + O_KEYS;
  const float* memb = mem + (size_t)b*T*UU;
  const float* keyb = keys + (size_t)b*T*UU;
  float* outb = out + (size_t)b*MELM*(steps*RRR);

  for (int i = tid; i < UU; i += 1024){ s_ha[i]=0.f; s_g1h[i]=0.f; s_g2h[i]=0.f; }
  if (tid < MELM) s_prev[tid] = 0.f;
  __syncthreads();

  const float4 v4 = reinterpret_cast<const float4*>(vvec)[lane];

  for (int step = 0; step < steps; ++step){
    // ---- Stage A: x1 = relu(Wp1 prev + bp1); gh_a/gh1/gh2 (depend only on carried state)
    if (tid < 64){
      int j4 = tid;
      float4 acc = gemv4<80,64>(ws + O_WP1T, s_prev, j4);
      float4 bb = reinterpret_cast<const float4*>(bp1)[j4];
      acc.x = fmaxf(acc.x+bb.x, 0.f); acc.y = fmaxf(acc.y+bb.y, 0.f);
      acc.z = fmaxf(acc.z+bb.z, 0.f); acc.w = fmaxf(acc.w+bb.w, 0.f);
      reinterpret_cast<float4*>(s_x1)[j4] = acc;
    } else if (tid < 256){
      int j4 = tid - 64;
      float4 acc = gemv4<256,192>(ws + O_WAHH, s_ha, j4);
      float4 bb = reinterpret_cast<const float4*>(ba_hh)[j4];
      acc.x+=bb.x; acc.y+=bb.y; acc.z+=bb.z; acc.w+=bb.w;
      reinterpret_cast<float4*>(s_gha)[j4] = acc;
    } else if (tid < 448){
      int j4 = tid - 256;
      float4 acc = gemv4<256,192>(ws + O_W1HH, s_g1h, j4);
      float4 bb = reinterpret_cast<const float4*>(b1_hh)[j4];
      acc.x+=bb.x; acc.y+=bb.y; acc.z+=bb.z; acc.w+=bb.w;
      reinterpret_cast<float4*>(s_gh1)[j4] = acc;
    } else if (tid < 640){
      int j4 = tid - 448;
      float4 acc = gemv4<256,192>(ws + O_W2HH, s_g2h, j4);
      float4 bb = reinterpret_cast<const float4*>(b2_hh)[j4];
      acc.x+=bb.x; acc.y+=bb.y; acc.z+=bb.z; acc.w+=bb.w;
      reinterpret_cast<float4*>(s_gh2)[j4] = acc;
    }
    __syncthreads();
    // ---- Stage B: x = relu(Wp2 x1 + bp2)   [128]
    if (tid < 32){
      float4 acc = gemv4<256,32>(ws + O_WP2T, s_x1, tid);
      float4 bb = reinterpret_cast<const float4*>(bp2)[tid];
      acc.x = fmaxf(acc.x+bb.x, 0.f); acc.y = fmaxf(acc.y+bb.y, 0.f);
      acc.z = fmaxf(acc.z+bb.z, 0.f); acc.w = fmaxf(acc.w+bb.w, 0.f);
      reinterpret_cast<float4*>(s_x)[tid] = acc;
    }
    __syncthreads();
    // ---- Stage C: gi_a = Wa_ih x + ba_ih   [768]
    if (tid < 192){
      float4 acc = gemv4<128,192>(ws + O_WAIH, s_x, tid);
      float4 bb = reinterpret_cast<const float4*>(ba_ih)[tid];
      acc.x+=bb.x; acc.y+=bb.y; acc.z+=bb.z; acc.w+=bb.w;
      reinterpret_cast<float4*>(s_gi)[tid] = acc;
    }
    __syncthreads();
    // ---- Stage D: attn GRU gates -> d_t (stored into s_ha)
    if (tid < 256){
      float r = fsig(s_gi[tid] + s_gha[tid]);
      float z = fsig(s_gi[256+tid] + s_gha[256+tid]);
      float n = ftanh(s_gi[512+tid] + r*s_gha[512+tid]);
      s_ha[tid] = (1.f - z)*n + z*s_ha[tid];
    }
    __syncthreads();
    // ---- Stage E: q = W2 d_t ; g1in (d_t half of Wproj) + bproj
    if (tid < 64){
      float4 acc = gemv4<256,64>(ws + O_W2T, s_ha, tid);
      reinterpret_cast<float4*>(s_q)[tid] = acc;
    } else if (tid < 128){
      int j4 = tid - 64;
      float4 acc = gemv4<256,64>(ws + O_WPROJ, s_ha, j4);
      float4 bb = reinterpret_cast<const float4*>(bproj)[j4];
      acc.x+=bb.x; acc.y+=bb.y; acc.z+=bb.z; acc.w+=bb.w;
      reinterpret_cast<float4*>(s_g1in)[j4] = acc;
    }
    __syncthreads();
    // ---- Stage F: scores[t] = tanh(keys[t]+q) . v  (wave per row)
    {
      const float4 q4 = reinterpret_cast<const float4*>(s_q)[lane];
      for (int t = wid; t < T; t += 16){
        const float4 k4 = reinterpret_cast<const float4*>(keyb + (size_t)t*UU)[lane];
        float sx = ftanh(k4.x+q4.x)*v4.x + ftanh(k4.y+q4.y)*v4.y
                 + ftanh(k4.z+q4.z)*v4.z + ftanh(k4.w+q4.w)*v4.w;
        #pragma unroll
        for (int o=32;o;o>>=1) sx += __shfl_xor(sx, o, 64);
        if (lane==0) s_sc[t] = sx;
      }
    }
    __syncthreads();
    // ---- Stage G: softmax over t (keep unnormalized exp in s_sc, 1/sum in s_scal[1])
    {
      float lm = -1e30f;
      for (int t = tid; t < T; t += 1024) lm = fmaxf(lm, s_sc[t]);
      #pragma unroll
      for (int o=32;o;o>>=1) lm = fmaxf(lm, __shfl_xor(lm, o, 64));
      if (lane==0) s_wred[wid] = lm;
      __syncthreads();
      if (tid==0){
        float m = s_wred[0];
        #pragma unroll
        for (int w2=1; w2<16; ++w2) m = fmaxf(m, s_wred[w2]);
        s_scal[0] = m;
      }
      __syncthreads();
      float M = s_scal[0];
      float ls = 0.f;
      for (int t = tid; t < T; t += 1024){
        float e = __expf(s_sc[t]-M);
        s_sc[t] = e; ls += e;
      }
      #pragma unroll
      for (int o=32;o;o>>=1) ls += __shfl_xor(ls, o, 64);
      if (lane==0) s_wred[wid] = ls;
      __syncthreads();
      if (tid==0){
        float s = 0.f;
        #pragma unroll
        for (int w2=0; w2<16; ++w2) s += s_wred[w2];
        s_scal[1] = 1.0f/s;
      }
      __syncthreads();
    }
    // ---- Stage H: ctx = (aw . memory) (wave partials + tree reduce)
    {
      float4 c4 = {0.f,0.f,0.f,0.f};
      for (int t = wid; t < T; t += 16){
        float w = s_sc[t];
        const float4 m4 = reinterpret_cast<const float4*>(memb + (size_t)t*UU)[lane];
        c4.x += w*m4.x; c4.y += w*m4.y; c4.z += w*m4.z; c4.w += w*m4.w;
      }
      reinterpret_cast<float4*>(s_red)[wid*64 + lane] = c4;
    }
    __syncthreads();
    if (tid < 256){
      float s = 0.f;
      #pragma unroll
      for (int w2=0; w2<16; ++w2) s += s_red[w2*256 + tid];
      s_ctx[tid] = s * s_scal[1];
    }
    __syncthreads();
    // ---- Stage I: g1in += Wproj(ctx half)
    if (tid < 64){
      float4 acc = gemv4<256,64>(ws + O_WPROJ + 256u*256u, s_ctx, tid);
      float4 cur = reinterpret_cast<float4*>(s_g1in)[tid];
      cur.x+=acc.x; cur.y+=acc.y; cur.z+=acc.z; cur.w+=acc.w;
      reinterpret_cast<float4*>(s_g1in)[tid] = cur;
    }
    __syncthreads();
    // ---- Stage J: gi1 = W1_ih g1in + b1_ih
    if (tid < 192){
      float4 acc = gemv4<256,192>(ws + O_W1IH, s_g1in, tid);
      float4 bb = reinterpret_cast<const float4*>(b1_ih)[tid];
      acc.x+=bb.x; acc.y+=bb.y; acc.z+=bb.z; acc.w+=bb.w;
      reinterpret_cast<float4*>(s_gi)[tid] = acc;
    }
    __syncthreads();
    // ---- Stage K: gru1 gates -> g1h; g2in = g1in + g1h
    if (tid < 256){
      float r = fsig(s_gi[tid] + s_gh1[tid]);
      float z = fsig(s_gi[256+tid] + s_gh1[256+tid]);
      float n = ftanh(s_gi[512+tid] + r*s_gh1[512+tid]);
      float hn = (1.f - z)*n + z*s_g1h[tid];
      s_g1h[tid] = hn;
      s_g2in[tid] = s_g1in[tid] + hn;
    }
    __syncthreads();
    // ---- Stage L: gi2 = W2_ih g2in + b2_ih
    if (tid < 192){
      float4 acc = gemv4<256,192>(ws + O_W2IH, s_g2in, tid);
      float4 bb = reinterpret_cast<const float4*>(b2_ih)[tid];
      acc.x+=bb.x; acc.y+=bb.y; acc.z+=bb.z; acc.w+=bb.w;
      reinterpret_cast<float4*>(s_gi)[tid] = acc;
    }
    __syncthreads();
    // ---- Stage M: gru2 gates -> g2h; s2 = g2in + g2h
    if (tid < 256){
      float r = fsig(s_gi[tid] + s_gh2[tid]);
      float z = fsig(s_gi[256+tid] + s_gh2[256+tid]);
      float n = ftanh(s_gi[512+tid] + r*s_gh2[512+tid]);
      float hn = (1.f - z)*n + z*s_g2h[tid];
      s_g2h[tid] = hn;
      s_s2[tid] = s_g2in[tid] + hn;
    }
    __syncthreads();
    // ---- Stage N: y = Wout s2 + bout; scatter to out; update prev
    if (tid < 100){
      float4 acc = gemv4<256,100>(ws + O_WOUT, s_s2, tid);
      float4 bb = reinterpret_cast<const float4*>(bout)[tid];
      acc.x+=bb.x; acc.y+=bb.y; acc.z+=bb.z; acc.w+=bb.w;
      float vals[4] = {acc.x, acc.y, acc.z, acc.w};
      #pragma unroll
      for (int d=0; d<4; ++d){
        int j = tid*4 + d;
        int mel = j/5, rr = j - mel*5;
        outb[(size_t)mel*(steps*RRR) + step*RRR + rr] = vals[d];
        if (rr == 4) s_prev[mel] = vals[d];
      }
    }
    __syncthreads();
  }
}

extern "C" void kernel_launch(void* const* d_in, const int* in_sizes, int n_in,
                              void* d_out, int out_size, void* d_ws, size_t ws_size,
                              hipStream_t stream)
{
  const float* mem  = (const float*)d_in[0];
  const float* Wp1  = (const float*)d_in[1];
  const float* bp1  = (const float*)d_in[2];
  const float* Wp2  = (const float*)d_in[3];
  const float* bp2  = (const float*)d_in[4];
  const float* W1   = (const float*)d_in[5];
  const float* W2   = (const float*)d_in[6];
  const float* vv   = (const float*)d_in[7];
  const float* Wa_ih= (const float*)d_in[8];
  const float* Wa_hh= (const float*)d_in[9];
  const float* ba_ih= (const float*)d_in[10];
  const float* ba_hh= (const float*)d_in[11];
  const float* W1_ih= (const float*)d_in[12];
  const float* W1_hh= (const float*)d_in[13];
  const float* b1_ih= (const float*)d_in[14];
  const float* b1_hh= (const float*)d_in[15];
  const float* W2_ih= (const float*)d_in[16];
  const float* W2_hh= (const float*)d_in[17];
  const float* b2_ih= (const float*)d_in[18];
  const float* b2_hh= (const float*)d_in[19];
  const float* Wproj= (const float*)d_in[20];
  const float* bproj= (const float*)d_in[21];
  const float* Wout = (const float*)d_in[22];
  const float* bout = (const float*)d_in[23];

  float* ws = (float*)d_ws;
  int T = in_sizes[0] / (BB*UU);
  int steps = T / RRR;

  auto tr = [&](const float* src, unsigned off, int N, int K){
    int total = N*K;
    k_transpose<<<dim3((total+255)/256), dim3(256), 0, stream>>>(src, ws + off, N, K);
  };
  tr(Wp1,   O_WP1T, 256, 80);
  tr(Wp2,   O_WP2T, 128, 256);
  tr(Wa_ih, O_WAIH, 768, 128);
  tr(Wa_hh, O_WAHH, 768, 256);
  tr(W2,    O_W2T,  256, 256);
  tr(Wproj, O_WPROJ,256, 512);
  tr(W1_ih, O_W1IH, 768, 256);
  tr(W1_hh, O_W1HH, 768, 256);
  tr(W2_ih, O_W2IH, 768, 256);
  tr(W2_hh, O_W2HH, 768, 256);
  tr(Wout,  O_WOUT, 400, 256);
  tr(W1,    O_W1T,  256, 256);

  k_keys<<<dim3((T+127)/128, UU/128, BB), dim3(256), 0, stream>>>(mem, ws + O_W1T, ws + O_KEYS, T);

  k_decode<<<dim3(BB), dim3(1024), 0, stream>>>(mem, ws,
      bp1, bp2, vv, ba_ih, ba_hh, b1_ih, b1_hh, b2_ih, b2_hh, bproj, bout,
      (float*)d_out, T, steps);
}